// Round 6
// baseline (3922.967 us; speedup 1.0000x reference)
//
#include <hip/hip_runtime.h>
#include <cstdint>

#define NB 65536   // batch
#define QB 16384   // quarter batch (bounds workspace to ~250 MB)

typedef __attribute__((ext_vector_type(4))) double f64x4;
typedef unsigned int u32;

// ---- promote all 5 weight matrices f32 -> f64 into one contiguous block ----
__global__ void promote_weights(const float* __restrict__ wqe1, const float* __restrict__ wqe2,
                                const float* __restrict__ wfus, const float* __restrict__ wg1,
                                const float* __restrict__ wg2, double* __restrict__ out) {
    int i = blockIdx.x * blockDim.x + threadIdx.x;
    if (i >= 1196032) return;
    float v;
    if (i < 262144)        v = wqe1[i];
    else if (i < 524288)   v = wqe2[i - 262144];
    else if (i < 1048576)  v = wfus[i - 524288];
    else if (i < 1179648)  v = wg1[i - 1048576];
    else                   v = wg2[i - 1179648];
    out[i] = (double)v;
}

// ---- fp64 NT GEMM: Out[M,N] = act(A[M,K] @ W[N,K]^T + bias), all f64 ----
// A cols [0,kSplit) from f32 Af (exact promote in-register); cols [kSplit,K) from f64 Ad.
// block = 256 thr (4 waves), tile 256x64, wave = 64x64 via 4x4 mfma_f64_16x16x4.
// K in blocks of 16: per lane one contiguous double4 (k = kg*4 + i); the k-permutation
// is applied to BOTH operands so the contraction is unchanged.
// f64 C/D layout: col = lane&15, row = (lane>>4) + 4*reg  [INTERLEAVED — round-5
// evidence: blocked mapping produced the involutive row swap 4g+b <-> g+4b, giving
// logits correct-per-token but token-shuffled (out0 pass / out1 fail at 2.95)].
template<int ACT>
__global__ __launch_bounds__(256) void gemm64(
    const float* __restrict__ Af, int ldaF, int kSplit,
    const double* __restrict__ Ad, int ldaD,
    const double* __restrict__ W,
    const float* __restrict__ bias,
    double* __restrict__ Out, int ldo, int K)
{
    const int lane = threadIdx.x & 63;
    const int wave = threadIdx.x >> 6;
    const int lr = lane & 15;     // 16-dim index (A row / W row / C col)
    const int kg = lane >> 4;     // k-group 0..3
    const int row0 = blockIdx.y * 256 + wave * 64;
    const int col0 = blockIdx.x * 64;

    f64x4 acc[4][4] = {};
    for (int kb = 0; kb < K; kb += 16) {
        f64x4 a4[4], w4[4];
        if (kb < kSplit) {
            #pragma unroll
            for (int mt = 0; mt < 4; ++mt) {
                const float* p = Af + (size_t)(row0 + mt * 16 + lr) * ldaF + kb + kg * 4;
                float4 f = *(const float4*)p;
                a4[mt][0] = (double)f.x; a4[mt][1] = (double)f.y;
                a4[mt][2] = (double)f.z; a4[mt][3] = (double)f.w;
            }
        } else {
            const int kp = kb - kSplit + kg * 4;
            #pragma unroll
            for (int mt = 0; mt < 4; ++mt)
                a4[mt] = *(const f64x4*)(Ad + (size_t)(row0 + mt * 16 + lr) * ldaD + kp);
        }
        #pragma unroll
        for (int nt = 0; nt < 4; ++nt)
            w4[nt] = *(const f64x4*)(W + (size_t)(col0 + nt * 16 + lr) * K + kb + kg * 4);
        #pragma unroll
        for (int i = 0; i < 4; ++i)
            #pragma unroll
            for (int mt = 0; mt < 4; ++mt)
                #pragma unroll
                for (int nt = 0; nt < 4; ++nt)
                    acc[mt][nt] = __builtin_amdgcn_mfma_f64_16x16x4f64(
                        a4[mt][i], w4[nt][i], acc[mt][nt], 0, 0, 0);
    }
    #pragma unroll
    for (int nt = 0; nt < 4; ++nt) {
        const int ncol = col0 + nt * 16 + lr;
        const double bv = bias ? (double)bias[ncol] : 0.0;
        #pragma unroll
        for (int mt = 0; mt < 4; ++mt) {
            #pragma unroll
            for (int r = 0; r < 4; ++r) {
                double v = acc[mt][nt][r] + bv;
                if (ACT == 1) v = v > 0.0 ? v : 0.0;
                if (ACT == 2) v = tanh(v);
                const int row = row0 + mt * 16 + kg + 4 * r;   // f64 interleaved C/D
                Out[(size_t)row * ldo + ncol] = v;
            }
        }
    }
}

// ---- f64 softmax + top-2 + renorm + scatter; one row/wave, lane = expert ----
__global__ void finalize_kernel(const double* __restrict__ L, float* __restrict__ out) {
    const int tid = blockIdx.x * blockDim.x + threadIdx.x;
    const int row = tid >> 6;
    const int e = tid & 63;
    if (row >= NB) return;
    double x = L[(size_t)row * 64 + e];
    out[(size_t)NB * 64 + (size_t)row * 64 + e] = (float)x;        // logits (output 1)
    double m = x;
    #pragma unroll
    for (int o = 32; o > 0; o >>= 1) m = fmax(m, __shfl_xor(m, o, 64));
    double p = exp(x - m);
    double s = p;
    #pragma unroll
    for (int o = 32; o > 0; o >>= 1) s += __shfl_xor(s, o, 64);
    double w = p / s;
    out[(size_t)(2 * NB) * 64 + (size_t)row * 64 + e] = (float)w;  // expert_weights (output 2)
    // top-1 (ties -> lowest index, matching jax.lax.top_k)
    double v1 = w;
    #pragma unroll
    for (int o = 32; o > 0; o >>= 1) v1 = fmax(v1, __shfl_xor(v1, o, 64));
    int i1 = (w == v1) ? e : 64;
    #pragma unroll
    for (int o = 32; o > 0; o >>= 1) i1 = min(i1, __shfl_xor(i1, o, 64));
    // top-2
    double wm = (e == i1) ? -1.0 : w;
    double v2 = wm;
    #pragma unroll
    for (int o = 32; o > 0; o >>= 1) v2 = fmax(v2, __shfl_xor(v2, o, 64));
    int i2 = (wm == v2) ? e : 64;
    #pragma unroll
    for (int o = 32; o > 0; o >>= 1) i2 = min(i2, __shfl_xor(i2, o, 64));
    const double denom = v1 + v2 + 1e-6;
    const double w1 = v1 / denom, w2 = v2 / denom;
    out[(size_t)row * 64 + e] = (e == i1) ? (float)w1 : ((e == i2) ? (float)w2 : 0.0f); // combine (output 0)
    if (e == 0) {
        float* idx = out + (size_t)(3 * NB) * 64 + (size_t)row * 2;  // top_k_indices (output 3)
        idx[0] = (float)i1;
        idx[1] = (float)i2;
    }
}

extern "C" void kernel_launch(void* const* d_in, const int* in_sizes, int n_in,
                              void* d_out, int out_size, void* d_ws, size_t ws_size,
                              hipStream_t stream) {
    const float* mm   = (const float*)d_in[0];   // [B,512]
    const float* qf   = (const float*)d_in[1];   // [B,512]
    const float* wqe1 = (const float*)d_in[2];
    const float* bqe1 = (const float*)d_in[3];
    const float* wqe2 = (const float*)d_in[4];
    const float* bqe2 = (const float*)d_in[5];
    const float* wfus = (const float*)d_in[6];
    const float* bfus = (const float*)d_in[7];
    const float* wg1  = (const float*)d_in[8];
    const float* wg2  = (const float*)d_in[9];
    float* out = (float*)d_out;

    char* ws = (char*)d_ws;
    double* wd = (double*)ws;                               // 1,196,032 f64 (9.6 MB)
    double* A  = (double*)(ws + ((size_t)16  << 20));       // [QB,512] f64 (67 MB)  h / fused
    double* Bq = (double*)(ws + ((size_t)96  << 20));       // [QB,512] f64 (67 MB)  q
    double* C  = (double*)(ws + ((size_t)176 << 20));       // [QB,256] f64 (34 MB)  t
    double* L  = (double*)(ws + ((size_t)216 << 20));       // [NB,64]  f64 (34 MB)  logits
    // top of use: ~250 MB

    promote_weights<<<4672, 256, 0, stream>>>(wqe1, wqe2, wfus, wg1, wg2, wd);

    for (int q = 0; q < 4; ++q) {
        const size_t ro = (size_t)q * QB;
        // G1: h = relu(qf @ Wqe1^T + b1)        A is f32 (exact promote)
        gemm64<1><<<dim3(8, QB / 256), 256, 0, stream>>>(
            qf + ro * 512, 512, 512, nullptr, 0, wd, bqe1, A, 512, 512);
        // G2: q = h @ Wqe2^T + b2
        gemm64<0><<<dim3(8, QB / 256), 256, 0, stream>>>(
            nullptr, 0, 0, A, 512, wd + 262144, bqe2, Bq, 512, 512);
        // G3: fused = relu([mm | q] @ Wfus^T + bf)   K=1024; cols<512 from f32 mm
        gemm64<1><<<dim3(8, QB / 256), 256, 0, stream>>>(
            mm + ro * 512, 512, 512, Bq, 512, wd + 524288, bfus, A, 512, 1024);
        // G4: t = tanh(fused @ Wg1^T)           N=256
        gemm64<2><<<dim3(4, QB / 256), 256, 0, stream>>>(
            nullptr, 0, 0, A, 512, wd + 1048576, nullptr, C, 256, 512);
        // G5: logits = t @ Wg2^T                N=64, K=256
        gemm64<0><<<dim3(1, QB / 256), 256, 0, stream>>>(
            nullptr, 0, 0, C, 256, wd + 1179648, nullptr, L + ro * 64, 64, 256);
    }

    finalize_kernel<<<NB * 64 / 256, 256, 0, stream>>>(L, out);
}

// Round 7
// 3231.807 us; speedup vs baseline: 1.2139x; 1.2139x over previous
//
#include <hip/hip_runtime.h>
#include <cstdint>

#define NB 65536   // batch
#define HB 32768   // half batch (2 passes bound workspace to ~304 MB)

typedef __attribute__((ext_vector_type(4))) double f64x4;

// ---- promote Wqe1, Wg1, Wg2 f32 -> f64 (Wqe2/Wfus handled by build_wg3) ----
__global__ void promote_weights(const float* __restrict__ wqe1, const float* __restrict__ wg1,
                                const float* __restrict__ wg2, double* __restrict__ out) {
    int i = blockIdx.x * blockDim.x + threadIdx.x;
    if (i >= 409600) return;
    float v;
    if (i < 262144)       v = wqe1[i];
    else if (i < 393216)  v = wg1[i - 262144];
    else                  v = wg2[i - 393216];
    out[i] = (double)v;
}

// ---- fold G2 into G3: Wg3[n,0:512] = Wfus[n,0:512];
//      Wg3[n,512+k] = sum_j Wfus[n,512+j] * Wqe2[j,k];  bcomb[n] = sum_j Wfus[n,512+j]*b2[j]
__global__ void build_wg3(const float* __restrict__ wfus, const float* __restrict__ wqe2,
                          const float* __restrict__ bqe2,
                          double* __restrict__ Wg3, double* __restrict__ bcomb) {
    int id = blockIdx.x * blockDim.x + threadIdx.x;   // 262144 threads
    int n = id >> 9, k = id & 511;
    Wg3[(size_t)n * 1024 + k] = (double)wfus[(size_t)n * 1024 + k];
    double s = 0.0;
    for (int j = 0; j < 512; ++j)
        s += (double)wfus[(size_t)n * 1024 + 512 + j] * (double)wqe2[(size_t)j * 512 + k];
    Wg3[(size_t)n * 1024 + 512 + k] = s;
    if (k == 0) {
        double b = 0.0;
        for (int j = 0; j < 512; ++j)
            b += (double)wfus[(size_t)n * 1024 + 512 + j] * (double)bqe2[j];
        bcomb[n] = b;
    }
}

// ---- fp64 NT GEMM: Out[M,N] = act(A[M,K] @ W[N,K]^T + biasF + bias64) ----
// 1-D grid with XCD-co-location swizzle: all nCol column-sibling blocks of a
// row-tile land on the SAME XCD (id&7), so each A line is HBM-fetched once.
// block = 256 thr (4 waves), tile 256x64, wave 64x64 via 4x4 mfma_f64_16x16x4.
// f64 C/D layout: col = lane&15, row = (lane>>4) + 4*reg  [round-6 verified].
template<int ACT>
__global__ __launch_bounds__(256) void gemm64(
    const float* __restrict__ Af, int ldaF, int kSplit,
    const double* __restrict__ Ad, int ldaD,
    const double* __restrict__ W,
    const float* __restrict__ biasF, const double* __restrict__ bias64,
    double* __restrict__ Out, int ldo, int K, int nCol)
{
    const int lane = threadIdx.x & 63;
    const int wave = threadIdx.x >> 6;
    const int lr = lane & 15;
    const int kg = lane >> 4;
    // XCD swizzle: rpx row-tiles per XCD; col-siblings consecutive -> same XCD
    const int id = blockIdx.x;
    const int xcd = id & 7;
    const int slot = id >> 3;
    const int rpx = (int)gridDim.x / (8 * nCol);
    const int rt = xcd * rpx + slot / nCol;
    const int col = slot % nCol;
    const int row0 = rt * 256 + wave * 64;
    const int col0 = col * 64;

    f64x4 acc[4][4] = {};
    for (int kb = 0; kb < K; kb += 16) {
        f64x4 a4[4], w4[4];
        if (kb < kSplit) {
            #pragma unroll
            for (int mt = 0; mt < 4; ++mt) {
                const float* p = Af + (size_t)(row0 + mt * 16 + lr) * ldaF + kb + kg * 4;
                float4 f = *(const float4*)p;
                a4[mt][0] = (double)f.x; a4[mt][1] = (double)f.y;
                a4[mt][2] = (double)f.z; a4[mt][3] = (double)f.w;
            }
        } else {
            const int kp = kb - kSplit + kg * 4;
            #pragma unroll
            for (int mt = 0; mt < 4; ++mt)
                a4[mt] = *(const f64x4*)(Ad + (size_t)(row0 + mt * 16 + lr) * ldaD + kp);
        }
        #pragma unroll
        for (int nt = 0; nt < 4; ++nt)
            w4[nt] = *(const f64x4*)(W + (size_t)(col0 + nt * 16 + lr) * K + kb + kg * 4);
        #pragma unroll
        for (int i = 0; i < 4; ++i)
            #pragma unroll
            for (int mt = 0; mt < 4; ++mt)
                #pragma unroll
                for (int nt = 0; nt < 4; ++nt)
                    acc[mt][nt] = __builtin_amdgcn_mfma_f64_16x16x4f64(
                        a4[mt][i], w4[nt][i], acc[mt][nt], 0, 0, 0);
    }
    #pragma unroll
    for (int nt = 0; nt < 4; ++nt) {
        const int ncol = col0 + nt * 16 + lr;
        double bv = biasF ? (double)biasF[ncol] : 0.0;
        if (bias64) bv += bias64[ncol];
        #pragma unroll
        for (int mt = 0; mt < 4; ++mt) {
            #pragma unroll
            for (int r = 0; r < 4; ++r) {
                double v = acc[mt][nt][r] + bv;
                if (ACT == 1) v = v > 0.0 ? v : 0.0;
                if (ACT == 2) v = tanh(v);
                const int row = row0 + mt * 16 + kg + 4 * r;   // f64 interleaved C/D
                Out[(size_t)row * ldo + ncol] = v;
            }
        }
    }
}

// ---- f64 softmax + top-2 + renorm + scatter; one row/wave, lane = expert ----
__global__ void finalize_kernel(const double* __restrict__ L, float* __restrict__ out) {
    const int tid = blockIdx.x * blockDim.x + threadIdx.x;
    const int row = tid >> 6;
    const int e = tid & 63;
    if (row >= NB) return;
    double x = L[(size_t)row * 64 + e];
    out[(size_t)NB * 64 + (size_t)row * 64 + e] = (float)x;        // logits (out 1)
    double m = x;
    #pragma unroll
    for (int o = 32; o > 0; o >>= 1) m = fmax(m, __shfl_xor(m, o, 64));
    double p = exp(x - m);
    double s = p;
    #pragma unroll
    for (int o = 32; o > 0; o >>= 1) s += __shfl_xor(s, o, 64);
    double w = p / s;
    out[(size_t)(2 * NB) * 64 + (size_t)row * 64 + e] = (float)w;  // expert_weights (out 2)
    double v1 = w;
    #pragma unroll
    for (int o = 32; o > 0; o >>= 1) v1 = fmax(v1, __shfl_xor(v1, o, 64));
    int i1 = (w == v1) ? e : 64;
    #pragma unroll
    for (int o = 32; o > 0; o >>= 1) i1 = min(i1, __shfl_xor(i1, o, 64));
    double wm = (e == i1) ? -1.0 : w;
    double v2 = wm;
    #pragma unroll
    for (int o = 32; o > 0; o >>= 1) v2 = fmax(v2, __shfl_xor(v2, o, 64));
    int i2 = (wm == v2) ? e : 64;
    #pragma unroll
    for (int o = 32; o > 0; o >>= 1) i2 = min(i2, __shfl_xor(i2, o, 64));
    const double denom = v1 + v2 + 1e-6;
    const double w1 = v1 / denom, w2 = v2 / denom;
    out[(size_t)row * 64 + e] = (e == i1) ? (float)w1 : ((e == i2) ? (float)w2 : 0.0f); // combine (out 0)
    if (e == 0) {
        float* idx = out + (size_t)(3 * NB) * 64 + (size_t)row * 2;  // indices (out 3)
        idx[0] = (float)i1;
        idx[1] = (float)i2;
    }
}

extern "C" void kernel_launch(void* const* d_in, const int* in_sizes, int n_in,
                              void* d_out, int out_size, void* d_ws, size_t ws_size,
                              hipStream_t stream) {
    const float* mm   = (const float*)d_in[0];   // [B,512]
    const float* qf   = (const float*)d_in[1];   // [B,512]
    const float* wqe1 = (const float*)d_in[2];
    const float* bqe1 = (const float*)d_in[3];
    const float* wqe2 = (const float*)d_in[4];
    const float* bqe2 = (const float*)d_in[5];
    const float* wfus = (const float*)d_in[6];
    const float* bfus = (const float*)d_in[7];
    const float* wg1  = (const float*)d_in[8];
    const float* wg2  = (const float*)d_in[9];
    float* out = (float*)d_out;

    char* ws = (char*)d_ws;
    double* wd    = (double*)ws;                          // Wqe1|Wg1|Wg2 f64 (3.3 MB)
    double* Wg3   = (double*)(ws + ((size_t)4  << 20));   // [512,1024] f64 (4 MB)
    double* bcomb = (double*)(ws + ((size_t)8  << 20));   // [512] f64
    double* L     = (double*)(ws + ((size_t)16 << 20));   // [NB,64]  f64 (32 MB)
    double* A     = (double*)(ws + ((size_t)48 << 20));   // [HB,512] f64 (128 MB)  h, then t(C) overlaps
    double* A2    = (double*)(ws + ((size_t)176 << 20));  // [HB,512] f64 (128 MB)  fused
    double* C     = A;                                    // [HB,256] f64 (64 MB), h dead by G4
    // top of use: 304 MB

    promote_weights<<<1600, 256, 0, stream>>>(wqe1, wg1, wg2, wd);
    build_wg3<<<1024, 256, 0, stream>>>(wfus, wqe2, bqe2, Wg3, bcomb);

    const double* Wqe1d = wd;
    const double* Wg1d  = wd + 262144;
    const double* Wg2d  = wd + 393216;

    for (int h = 0; h < 2; ++h) {
        const size_t ro = (size_t)h * HB;
        // G1: h = relu(qf @ Wqe1^T + b1)         [A f32 in-register promote]
        gemm64<1><<<HB / 256 * 8, 256, 0, stream>>>(
            qf + ro * 512, 512, 512, nullptr, 0, Wqe1d, bqe1, nullptr, A, 512, 512, 8);
        // G3': fused = relu(mm@Wf1^T + h@Wcomb^T + bfus + bcomb)   K=1024
        gemm64<1><<<HB / 256 * 8, 256, 0, stream>>>(
            mm + ro * 512, 512, 512, A, 512, Wg3, bfus, bcomb, A2, 512, 1024, 8);
        // G4: t = tanh(fused @ Wg1^T)            N=256
        gemm64<2><<<HB / 256 * 4, 256, 0, stream>>>(
            nullptr, 0, 0, A2, 512, Wg1d, nullptr, nullptr, C, 256, 512, 4);
        // G5: logits = t @ Wg2^T                 N=64, K=256
        gemm64<0><<<HB / 256 * 1, 256, 0, stream>>>(
            nullptr, 0, 0, C, 256, Wg2d, nullptr, nullptr, L + ro * 64, 64, 256, 1);
    }

    finalize_kernel<<<NB * 64 / 256, 256, 0, stream>>>(L, out);
}

// Round 8
// 2916.342 us; speedup vs baseline: 1.3452x; 1.1082x over previous
//
#include <hip/hip_runtime.h>
#include <cstdint>

#define NB 65536   // batch
#define HB 32768   // half batch (2 passes bound workspace to ~304 MB)

typedef __attribute__((ext_vector_type(4))) double f64x4;

// ---- promote Wqe1, Wg1, Wg2 f32 -> f64 (Wqe2/Wfus handled by build_wg3) ----
__global__ void promote_weights(const float* __restrict__ wqe1, const float* __restrict__ wg1,
                                const float* __restrict__ wg2, double* __restrict__ out) {
    int i = blockIdx.x * blockDim.x + threadIdx.x;
    if (i >= 409600) return;
    float v;
    if (i < 262144)       v = wqe1[i];
    else if (i < 393216)  v = wg1[i - 262144];
    else                  v = wg2[i - 393216];
    out[i] = (double)v;
}

// ---- fold G2 into G3: Wg3[n,0:512] = Wfus[n,0:512];
//      Wg3[n,512+k] = sum_j Wfus[n,512+j] * Wqe2[j,k];  bcomb[n] = sum_j Wfus[n,512+j]*b2[j]
__global__ void build_wg3(const float* __restrict__ wfus, const float* __restrict__ wqe2,
                          const float* __restrict__ bqe2,
                          double* __restrict__ Wg3, double* __restrict__ bcomb) {
    int id = blockIdx.x * blockDim.x + threadIdx.x;   // 262144 threads
    int n = id >> 9, k = id & 511;
    Wg3[(size_t)n * 1024 + k] = (double)wfus[(size_t)n * 1024 + k];
    double s = 0.0;
    for (int j = 0; j < 512; ++j)
        s += (double)wfus[(size_t)n * 1024 + 512 + j] * (double)wqe2[(size_t)j * 512 + k];
    Wg3[(size_t)n * 1024 + 512 + k] = s;
    if (k == 0) {
        double b = 0.0;
        for (int j = 0; j < 512; ++j)
            b += (double)wfus[(size_t)n * 1024 + 512 + j] * (double)bqe2[j];
        bcomb[n] = b;
    }
}

// ---- fp64 NT GEMM: Out[M,N] = act(A[M,K] @ W[N,K]^T + biasF + bias64) ----
// 512 threads / 8 waves: 4 row-waves x 2 col-waves; block tile 256x64,
// wave tile 64x32 via 4x2 mfma_f64_16x16x4 (acc = 64 AGPR -> 2 waves/SIMD).
// XCD co-location swizzle: all nCol column-sibling blocks of a row-tile land
// on the SAME XCD (id&7) so each A line is HBM-fetched once [round-7 verified:
// FETCH 397->164 MB]. f64 C/D: col=lane&15, row=(lane>>4)+4*reg [round-6 verified].
template<int ACT>
__global__ __launch_bounds__(512, 2) void gemm64(
    const float* __restrict__ Af, int ldaF, int kSplit,
    const double* __restrict__ Ad, int ldaD,
    const double* __restrict__ W,
    const float* __restrict__ biasF, const double* __restrict__ bias64,
    double* __restrict__ Out, int ldo, int K, int nCol)
{
    const int lane = threadIdx.x & 63;
    const int wave = threadIdx.x >> 6;   // 0..7
    const int rw = wave & 3;             // row-wave 0..3
    const int cw = wave >> 2;            // col-wave 0..1
    const int lr = lane & 15;
    const int kg = lane >> 4;
    const int id = blockIdx.x;
    const int xcd = id & 7;
    const int slot = id >> 3;
    const int rpx = (int)gridDim.x / (8 * nCol);
    const int rt = xcd * rpx + slot / nCol;
    const int col = slot % nCol;
    const int row0 = rt * 256 + rw * 64;
    const int col0 = col * 64 + cw * 32;

    f64x4 acc[4][2] = {};
    for (int kb = 0; kb < K; kb += 16) {
        f64x4 a4[4], w4[2];
        if (kb < kSplit) {
            #pragma unroll
            for (int mt = 0; mt < 4; ++mt) {
                const float* p = Af + (size_t)(row0 + mt * 16 + lr) * ldaF + kb + kg * 4;
                float4 f = *(const float4*)p;
                a4[mt][0] = (double)f.x; a4[mt][1] = (double)f.y;
                a4[mt][2] = (double)f.z; a4[mt][3] = (double)f.w;
            }
        } else {
            const int kp = kb - kSplit + kg * 4;
            #pragma unroll
            for (int mt = 0; mt < 4; ++mt)
                a4[mt] = *(const f64x4*)(Ad + (size_t)(row0 + mt * 16 + lr) * ldaD + kp);
        }
        #pragma unroll
        for (int nt = 0; nt < 2; ++nt)
            w4[nt] = *(const f64x4*)(W + (size_t)(col0 + nt * 16 + lr) * K + kb + kg * 4);
        #pragma unroll
        for (int i = 0; i < 4; ++i)
            #pragma unroll
            for (int mt = 0; mt < 4; ++mt)
                #pragma unroll
                for (int nt = 0; nt < 2; ++nt)
                    acc[mt][nt] = __builtin_amdgcn_mfma_f64_16x16x4f64(
                        a4[mt][i], w4[nt][i], acc[mt][nt], 0, 0, 0);
    }
    #pragma unroll
    for (int nt = 0; nt < 2; ++nt) {
        const int ncol = col0 + nt * 16 + lr;
        double bv = biasF ? (double)biasF[ncol] : 0.0;
        if (bias64) bv += bias64[ncol];
        #pragma unroll
        for (int mt = 0; mt < 4; ++mt) {
            #pragma unroll
            for (int r = 0; r < 4; ++r) {
                double v = acc[mt][nt][r] + bv;
                if (ACT == 1) v = v > 0.0 ? v : 0.0;
                if (ACT == 2) v = tanh(v);
                const int row = row0 + mt * 16 + kg + 4 * r;   // f64 interleaved C/D
                Out[(size_t)row * ldo + ncol] = v;
            }
        }
    }
}

// ---- f64 softmax + top-2 + renorm + scatter; one row/wave, lane = expert ----
__global__ void finalize_kernel(const double* __restrict__ L, float* __restrict__ out) {
    const int tid = blockIdx.x * blockDim.x + threadIdx.x;
    const int row = tid >> 6;
    const int e = tid & 63;
    if (row >= NB) return;
    double x = L[(size_t)row * 64 + e];
    out[(size_t)NB * 64 + (size_t)row * 64 + e] = (float)x;        // logits (out 1)
    double m = x;
    #pragma unroll
    for (int o = 32; o > 0; o >>= 1) m = fmax(m, __shfl_xor(m, o, 64));
    double p = exp(x - m);
    double s = p;
    #pragma unroll
    for (int o = 32; o > 0; o >>= 1) s += __shfl_xor(s, o, 64);
    double w = p / s;
    out[(size_t)(2 * NB) * 64 + (size_t)row * 64 + e] = (float)w;  // expert_weights (out 2)
    double v1 = w;
    #pragma unroll
    for (int o = 32; o > 0; o >>= 1) v1 = fmax(v1, __shfl_xor(v1, o, 64));
    int i1 = (w == v1) ? e : 64;
    #pragma unroll
    for (int o = 32; o > 0; o >>= 1) i1 = min(i1, __shfl_xor(i1, o, 64));
    double wm = (e == i1) ? -1.0 : w;
    double v2 = wm;
    #pragma unroll
    for (int o = 32; o > 0; o >>= 1) v2 = fmax(v2, __shfl_xor(v2, o, 64));
    int i2 = (wm == v2) ? e : 64;
    #pragma unroll
    for (int o = 32; o > 0; o >>= 1) i2 = min(i2, __shfl_xor(i2, o, 64));
    const double denom = v1 + v2 + 1e-6;
    const double w1 = v1 / denom, w2 = v2 / denom;
    out[(size_t)row * 64 + e] = (e == i1) ? (float)w1 : ((e == i2) ? (float)w2 : 0.0f); // combine (out 0)
    if (e == 0) {
        float* idx = out + (size_t)(3 * NB) * 64 + (size_t)row * 2;  // indices (out 3)
        idx[0] = (float)i1;
        idx[1] = (float)i2;
    }
}

extern "C" void kernel_launch(void* const* d_in, const int* in_sizes, int n_in,
                              void* d_out, int out_size, void* d_ws, size_t ws_size,
                              hipStream_t stream) {
    const float* mm   = (const float*)d_in[0];   // [B,512]
    const float* qf   = (const float*)d_in[1];   // [B,512]
    const float* wqe1 = (const float*)d_in[2];
    const float* bqe1 = (const float*)d_in[3];
    const float* wqe2 = (const float*)d_in[4];
    const float* bqe2 = (const float*)d_in[5];
    const float* wfus = (const float*)d_in[6];
    const float* bfus = (const float*)d_in[7];
    const float* wg1  = (const float*)d_in[8];
    const float* wg2  = (const float*)d_in[9];
    float* out = (float*)d_out;

    char* ws = (char*)d_ws;
    double* wd    = (double*)ws;                          // Wqe1|Wg1|Wg2 f64 (3.3 MB)
    double* Wg3   = (double*)(ws + ((size_t)4  << 20));   // [512,1024] f64 (4 MB)
    double* bcomb = (double*)(ws + ((size_t)8  << 20));   // [512] f64
    double* L     = (double*)(ws + ((size_t)16 << 20));   // [NB,64]  f64 (32 MB)
    double* A     = (double*)(ws + ((size_t)48 << 20));   // [HB,512] f64 (128 MB)  h; C overlaps
    double* A2    = (double*)(ws + ((size_t)176 << 20));  // [HB,512] f64 (128 MB)  fused
    double* C     = A;                                    // [HB,256] f64, h dead by G4
    // top of use: 304 MB

    promote_weights<<<1600, 256, 0, stream>>>(wqe1, wg1, wg2, wd);
    build_wg3<<<1024, 256, 0, stream>>>(wfus, wqe2, bqe2, Wg3, bcomb);

    const double* Wqe1d = wd;
    const double* Wg1d  = wd + 262144;
    const double* Wg2d  = wd + 393216;

    for (int h = 0; h < 2; ++h) {
        const size_t ro = (size_t)h * HB;
        // G1: h = relu(qf @ Wqe1^T + b1)         [A f32 in-register promote]
        gemm64<1><<<HB / 256 * 8, 512, 0, stream>>>(
            qf + ro * 512, 512, 512, nullptr, 0, Wqe1d, bqe1, nullptr, A, 512, 512, 8);
        // G3': fused = relu(mm@Wf1^T + h@Wcomb^T + bfus + bcomb)   K=1024
        gemm64<1><<<HB / 256 * 8, 512, 0, stream>>>(
            mm + ro * 512, 512, 512, A, 512, Wg3, bfus, bcomb, A2, 512, 1024, 8);
        // G4: t = tanh(fused @ Wg1^T)            N=256
        gemm64<2><<<HB / 256 * 4, 512, 0, stream>>>(
            nullptr, 0, 0, A2, 512, Wg1d, nullptr, nullptr, C, 256, 512, 4);
        // G5: logits = t @ Wg2^T                 N=64, K=256
        gemm64<0><<<HB / 256 * 1, 512, 0, stream>>>(
            nullptr, 0, 0, C, 256, Wg2d, nullptr, nullptr, L + ro * 64, 64, 256, 1);
    }

    finalize_kernel<<<NB * 64 / 256, 256, 0, stream>>>(L, out);
}